// Round 1
// baseline (806.139 us; speedup 1.0000x reference)
//
#include <hip/hip_runtime.h>
#include <hip/hip_bf16.h>
#include <math.h>

#define Dm 1024
#define Hn 16
#define HDm 64
#define FFm 4096
#define Sn 2048
#define SEG 512
#define EPSV 1e-6f

typedef __attribute__((ext_vector_type(4))) float f32x4;
typedef __attribute__((ext_vector_type(8))) short s16x8;
typedef __attribute__((ext_vector_type(4))) short s16x4;

__device__ inline short f2bf(float f) {
  __hip_bfloat16 h = __float2bfloat16(f);
  short s;
  __builtin_memcpy(&s, &h, 2);
  return s;
}

__device__ inline float wred_sum(float v) {
#pragma unroll
  for (int m = 32; m > 0; m >>= 1) v += __shfl_xor(v, m, 64);
  return v;
}
__device__ inline float wred_max(float v) {
#pragma unroll
  for (int m = 32; m > 0; m >>= 1) v = fmaxf(v, __shfl_xor(v, m, 64));
  return v;
}

// ---------------- LayerNorm: fp32 in -> bf16 out ----------------
__global__ __launch_bounds__(256) void ln_kernel(const float* __restrict__ x,
                                                 const float* __restrict__ g,
                                                 const float* __restrict__ b,
                                                 short* __restrict__ out) {
  const int row = blockIdx.x;
  const int tid = threadIdx.x;
  f32x4 v = *reinterpret_cast<const f32x4*>(x + (size_t)row * Dm + tid * 4);
  float s1 = v.x + v.y + v.z + v.w;
  float s2 = v.x * v.x + v.y * v.y + v.z * v.z + v.w * v.w;
  s1 = wred_sum(s1);
  s2 = wred_sum(s2);
  __shared__ float t1[4], t2[4];
  if ((tid & 63) == 0) { t1[tid >> 6] = s1; t2[tid >> 6] = s2; }
  __syncthreads();
  s1 = t1[0] + t1[1] + t1[2] + t1[3];
  s2 = t2[0] + t2[1] + t2[2] + t2[3];
  const float mean = s1 * (1.0f / Dm);
  const float var = s2 * (1.0f / Dm) - mean * mean;
  const float rstd = rsqrtf(var + EPSV);
  f32x4 gv = *reinterpret_cast<const f32x4*>(g + tid * 4);
  f32x4 bv = *reinterpret_cast<const f32x4*>(b + tid * 4);
  s16x4 o;
#pragma unroll
  for (int j = 0; j < 4; ++j)
    o[j] = f2bf((v[j] - mean) * rstd * gv[j] + bv[j]);
  *reinterpret_cast<s16x4*>(out + (size_t)row * Dm + tid * 4) = o;
}

// ------------- RoPE on q,k (fp32 qkv) -> bf16 q,k ; v -> bf16 V^T -------------
__global__ __launch_bounds__(256) void rope_kernel(const float* __restrict__ qkv,
                                                   const float* __restrict__ cosb,
                                                   const float* __restrict__ sinb,
                                                   short* __restrict__ qb,
                                                   short* __restrict__ kb,
                                                   short* __restrict__ vT) {
  const int s = blockIdx.x;
  const int tid = threadIdx.x;
  const float* rowq = qkv + (size_t)s * 3 * Dm;
#pragma unroll
  for (int it = 0; it < 4; ++it) {
    const int i = tid + it * 256;
    const int d = i & 63;
    const float c = cosb[(size_t)s * HDm + d];
    const float sn = sinb[(size_t)s * HDm + d];
    const int pi = (d < 32) ? i + 32 : i - 32;
    const float sgn = (d < 32) ? -1.0f : 1.0f;
    const float qv = rowq[i], qp = rowq[pi];
    qb[(size_t)s * Dm + i] = f2bf(qv * c + sgn * qp * sn);
    const float kv = rowq[Dm + i], kp = rowq[Dm + pi];
    kb[(size_t)s * Dm + i] = f2bf(kv * c + sgn * kp * sn);
    vT[(size_t)i * Sn + s] = f2bf(rowq[2 * Dm + i]);
  }
}

// -------- softmax over 512-length rows; fp32 in, bf16 out in-place --------
__global__ __launch_bounds__(128) void softmax_kernel(float* __restrict__ scores) {
  const size_t rowoff = ((size_t)blockIdx.y * SEG + blockIdx.x) * SEG;
  float* rp = scores + rowoff;
  const int tid = threadIdx.x;
  f32x4 v = *reinterpret_cast<const f32x4*>(rp + tid * 4);
  float mx = fmaxf(fmaxf(v.x, v.y), fmaxf(v.z, v.w));
  mx = wred_max(mx);
  __shared__ float rmax[2], rsum[2];
  if ((tid & 63) == 0) rmax[tid >> 6] = mx;
  __syncthreads();
  mx = fmaxf(rmax[0], rmax[1]);
  f32x4 e;
#pragma unroll
  for (int j = 0; j < 4; ++j) e[j] = __expf(v[j] - mx);
  float sm = e.x + e.y + e.z + e.w;
  sm = wred_sum(sm);
  if ((tid & 63) == 0) rsum[tid >> 6] = sm;
  __syncthreads();
  const float inv = 1.0f / (rsum[0] + rsum[1]);
  s16x4 o;
#pragma unroll
  for (int j = 0; j < 4; ++j) o[j] = f2bf(e[j] * inv);
  *reinterpret_cast<s16x4*>(reinterpret_cast<short*>(rp) + tid * 4) = o;
}

// -------- weight transpose + convert: W (K x N fp32) -> Wt (N x K bf16) --------
__global__ __launch_bounds__(256) void wt_kernel(const float* __restrict__ W,
                                                 short* __restrict__ Wt,
                                                 int K, int N) {
  __shared__ float t[32][33];
  const int n0 = blockIdx.x * 32, k0 = blockIdx.y * 32;
  const int tx = threadIdx.x & 31, ty = threadIdx.x >> 5;  // ty 0..7
#pragma unroll
  for (int r = 0; r < 32; r += 8)
    t[r + ty][tx] = W[(size_t)(k0 + r + ty) * N + n0 + tx];
  __syncthreads();
#pragma unroll
  for (int r = 0; r < 32; r += 8)
    Wt[(size_t)(n0 + r + ty) * K + k0 + tx] = f2bf(t[tx][r + ty]);
}

// ---------------- GEMM: C = A (MxK) * Bt^T (Bt is NxK) ----------------
// MODE 0: dense (z unused). MODE 1: QK^T batched. MODE 2: PV batched.
struct GemmArgs {
  const short* A; int lda;
  const short* B; int ldb;
  void* C; int ldc;
  int M, N, K;
  const float* bias;
  const float* res; int ldres;
  float scale;
};

template <int MODE, int OBF16, int BIAS, int RES, int GELU>
__global__ __launch_bounds__(256) void gemm_kernel(GemmArgs p) {
  const int z = blockIdx.z;
  const short* A = p.A;
  const short* B = p.B;
  char* Cb = (char*)p.C;
  if (MODE == 1) {
    const int seg = z & 3, hh = z >> 2;
    A += (size_t)(seg * SEG) * p.lda + hh * HDm;
    B += (size_t)(seg * SEG) * p.ldb + hh * HDm;
    Cb += (size_t)z * SEG * SEG * 4;
  } else if (MODE == 2) {
    const int seg = z & 3, hh = z >> 2;
    A += (size_t)z * SEG * 1024;
    B += (size_t)hh * HDm * p.ldb + seg * SEG;
    Cb += ((size_t)seg * SEG * 1024 + (size_t)hh * HDm) * 2;
  }
  __shared__ short As[128 * 72];
  __shared__ short Bs[128 * 72];
  const int tid = threadIdx.x;
  const int lane = tid & 63;
  const int wave = tid >> 6;
  const int wr = (wave >> 1) * 64;
  const int wc = (wave & 1) * 64;
  const int tileM = blockIdx.y * 128;
  const int tileN = blockIdx.x * 128;
  const int l15 = lane & 15;
  const int lg = lane >> 4;

  f32x4 acc[4][4] = {};

  const int nkt = p.K >> 6;
  for (int kt = 0; kt < nkt; ++kt) {
    const int k0 = kt * 64;
#pragma unroll
    for (int j = 0; j < 4; ++j) {
      const int c = tid + j * 256;
      const int row = c >> 3, col8 = (c & 7) * 8;
      s16x8 v = *reinterpret_cast<const s16x8*>(
          A + (size_t)(tileM + row) * p.lda + k0 + col8);
      *reinterpret_cast<s16x8*>(&As[row * 72 + col8]) = v;
    }
#pragma unroll
    for (int j = 0; j < 4; ++j) {
      const int c = tid + j * 256;
      const int row = c >> 3, col8 = (c & 7) * 8;
      s16x8 v = {};
      if (tileN + row < p.N)
        v = *reinterpret_cast<const s16x8*>(
            B + (size_t)(tileN + row) * p.ldb + k0 + col8);
      *reinterpret_cast<s16x8*>(&Bs[row * 72 + col8]) = v;
    }
    __syncthreads();
#pragma unroll
    for (int kk = 0; kk < 64; kk += 32) {
      s16x8 af[4], bfr[4];
#pragma unroll
      for (int f = 0; f < 4; ++f)
        af[f] = *reinterpret_cast<const s16x8*>(
            &As[(wr + f * 16 + l15) * 72 + kk + lg * 8]);
#pragma unroll
      for (int f = 0; f < 4; ++f)
        bfr[f] = *reinterpret_cast<const s16x8*>(
            &Bs[(wc + f * 16 + l15) * 72 + kk + lg * 8]);
#pragma unroll
      for (int fi = 0; fi < 4; ++fi)
#pragma unroll
        for (int fj = 0; fj < 4; ++fj)
          acc[fi][fj] = __builtin_amdgcn_mfma_f32_16x16x32_bf16(
              af[fi], bfr[fj], acc[fi][fj], 0, 0, 0);
    }
    __syncthreads();
  }

#pragma unroll
  for (int fi = 0; fi < 4; ++fi) {
#pragma unroll
    for (int fj = 0; fj < 4; ++fj) {
#pragma unroll
      for (int r = 0; r < 4; ++r) {
        const int row = tileM + wr + fi * 16 + lg * 4 + r;
        const int col = tileN + wc + fj * 16 + l15;
        if (col < p.N) {
          float v = acc[fi][fj][r] * p.scale;
          if (BIAS) v += p.bias[col];
          if (GELU) v = 0.5f * v * (1.0f + erff(v * 0.70710678118654752f));
          if (RES) v += p.res[(size_t)row * p.ldres + col];
          if (OBF16)
            reinterpret_cast<short*>(Cb)[(size_t)row * p.ldc + col] = f2bf(v);
          else
            reinterpret_cast<float*>(Cb)[(size_t)row * p.ldc + col] = v;
        }
      }
    }
  }
}

extern "C" void kernel_launch(void* const* d_in, const int* in_sizes, int n_in,
                              void* d_out, int out_size, void* d_ws, size_t ws_size,
                              hipStream_t stream) {
  const float* x0 = (const float*)d_in[0];
  const float* cosb = (const float*)d_in[2];
  const float* sinb = (const float*)d_in[3];
  const float* ln1_g = (const float*)d_in[4];
  const float* ln1_b = (const float*)d_in[5];
  const float* qkv_w = (const float*)d_in[6];
  const float* qkv_b = (const float*)d_in[7];
  const float* proj_w = (const float*)d_in[8];
  const float* proj_b = (const float*)d_in[9];
  const float* ln2_g = (const float*)d_in[10];
  const float* ln2_b = (const float*)d_in[11];
  const float* fc1_w = (const float*)d_in[12];
  const float* fc1_b = (const float*)d_in[13];
  const float* fc2_w = (const float*)d_in[14];
  const float* fc2_b = (const float*)d_in[15];

  char* ws = (char*)d_ws;
  size_t off = 0;
  auto alloc = [&](size_t bytes) {
    void* p = ws + off;
    off += (bytes + 255) & ~(size_t)255;
    return p;
  };
  short* wqkvT = (short*)alloc((size_t)2 * 3072 * 1024 * 2);
  short* wprojT = (short*)alloc((size_t)2 * 1024 * 1024 * 2);
  short* wfc1T = (short*)alloc((size_t)2 * 4096 * 1024 * 2);
  short* wfc2T = (short*)alloc((size_t)2 * 1024 * 4096 * 2);
  float* xbuf = (float*)alloc((size_t)Sn * Dm * 4);
  short* hbuf = (short*)alloc((size_t)Sn * Dm * 2);
  float* qkv = (float*)alloc((size_t)Sn * 3 * Dm * 4);
  short* qb = (short*)alloc((size_t)Sn * Dm * 2);
  short* kb = (short*)alloc((size_t)Sn * Dm * 2);
  short* vT = (short*)alloc((size_t)Sn * Dm * 2);
  float* scores = (float*)alloc((size_t)64 * SEG * SEG * 4);
  short* ao = (short*)alloc((size_t)Sn * Dm * 2);
  short* ffn = (short*)alloc((size_t)Sn * FFm * 2);
  (void)ws_size; (void)in_sizes; (void)n_in; (void)out_size;

  // weight transpose+convert (per call; stateless)
  for (int i = 0; i < 2; ++i) {
    wt_kernel<<<dim3(96, 32), 256, 0, stream>>>(
        qkv_w + (size_t)i * Dm * 3072, wqkvT + (size_t)i * 3072 * Dm, Dm, 3072);
    wt_kernel<<<dim3(32, 32), 256, 0, stream>>>(
        proj_w + (size_t)i * Dm * Dm, wprojT + (size_t)i * Dm * Dm, Dm, Dm);
    wt_kernel<<<dim3(128, 32), 256, 0, stream>>>(
        fc1_w + (size_t)i * Dm * FFm, wfc1T + (size_t)i * FFm * Dm, Dm, FFm);
    wt_kernel<<<dim3(32, 128), 256, 0, stream>>>(
        fc2_w + (size_t)i * FFm * Dm, wfc2T + (size_t)i * Dm * FFm, FFm, Dm);
  }

  for (int i = 0; i < 2; ++i) {
    const float* xin = i ? (const float*)xbuf : x0;

    ln_kernel<<<dim3(Sn), 256, 0, stream>>>(xin, ln1_g + i * Dm, ln1_b + i * Dm, hbuf);

    {  // qkv = h @ Wqkv + b  (fp32 out)
      GemmArgs p = {};
      p.A = hbuf; p.lda = Dm;
      p.B = wqkvT + (size_t)i * 3072 * Dm; p.ldb = Dm;
      p.C = qkv; p.ldc = 3 * Dm;
      p.M = Sn; p.N = 3 * Dm; p.K = Dm;
      p.bias = qkv_b + i * 3 * Dm; p.scale = 1.0f;
      gemm_kernel<0, 0, 1, 0, 0><<<dim3(24, 16, 1), 256, 0, stream>>>(p);
    }

    rope_kernel<<<dim3(Sn), 256, 0, stream>>>(qkv, cosb, sinb, qb, kb, vT);

    {  // scores = scale * q @ k^T  per (head, seg)
      GemmArgs p = {};
      p.A = qb; p.lda = Dm;
      p.B = kb; p.ldb = Dm;
      p.C = scores; p.ldc = SEG;
      p.M = SEG; p.N = SEG; p.K = HDm;
      p.scale = 0.125f;
      gemm_kernel<1, 0, 0, 0, 0><<<dim3(4, 4, 64), 256, 0, stream>>>(p);
    }

    softmax_kernel<<<dim3(SEG, 64), 128, 0, stream>>>(scores);

    {  // ao = probs @ V  per (head, seg)  (bf16 out)
      GemmArgs p = {};
      p.A = (const short*)scores; p.lda = 1024;
      p.B = vT; p.ldb = Sn;
      p.C = ao; p.ldc = Dm;
      p.M = SEG; p.N = HDm; p.K = SEG;
      p.scale = 1.0f;
      gemm_kernel<2, 1, 0, 0, 0><<<dim3(1, 4, 64), 256, 0, stream>>>(p);
    }

    {  // x = xin + ao @ Wproj + b  (fp32 out)
      GemmArgs p = {};
      p.A = ao; p.lda = Dm;
      p.B = wprojT + (size_t)i * Dm * Dm; p.ldb = Dm;
      p.C = xbuf; p.ldc = Dm;
      p.M = Sn; p.N = Dm; p.K = Dm;
      p.bias = proj_b + i * Dm; p.res = xin; p.ldres = Dm; p.scale = 1.0f;
      gemm_kernel<0, 0, 1, 1, 0><<<dim3(8, 16, 1), 256, 0, stream>>>(p);
    }

    ln_kernel<<<dim3(Sn), 256, 0, stream>>>(xbuf, ln2_g + i * Dm, ln2_b + i * Dm, hbuf);

    {  // ffn = gelu(h2 @ Wfc1 + b)  (bf16 out)
      GemmArgs p = {};
      p.A = hbuf; p.lda = Dm;
      p.B = wfc1T + (size_t)i * FFm * Dm; p.ldb = Dm;
      p.C = ffn; p.ldc = FFm;
      p.M = Sn; p.N = FFm; p.K = Dm;
      p.bias = fc1_b + i * FFm; p.scale = 1.0f;
      gemm_kernel<0, 1, 1, 0, 1><<<dim3(32, 16, 1), 256, 0, stream>>>(p);
    }

    {  // x = x + ffn @ Wfc2 + b  (fp32 out; layer 2 -> d_out)
      GemmArgs p = {};
      p.A = ffn; p.lda = FFm;
      p.B = wfc2T + (size_t)i * Dm * FFm; p.ldb = FFm;
      p.C = (i == 1) ? d_out : (void*)xbuf; p.ldc = Dm;
      p.M = Sn; p.N = Dm; p.K = FFm;
      p.bias = fc2_b + i * Dm; p.res = xbuf; p.ldres = Dm; p.scale = 1.0f;
      gemm_kernel<0, 0, 1, 1, 0><<<dim3(8, 16, 1), 256, 0, stream>>>(p);
    }
  }
}

// Round 2
// 529.512 us; speedup vs baseline: 1.5224x; 1.5224x over previous
//
#include <hip/hip_runtime.h>
#include <hip/hip_bf16.h>
#include <math.h>

#define Dm 1024
#define Hn 16
#define HDm 64
#define FFm 4096
#define Sn 2048
#define SEG 512
#define EPSV 1e-6f

typedef __attribute__((ext_vector_type(4))) float f32x4;
typedef __attribute__((ext_vector_type(8))) short s16x8;
typedef __attribute__((ext_vector_type(4))) short s16x4;

__device__ inline short f2bf(float f) {
  __hip_bfloat16 h = __float2bfloat16(f);
  short s;
  __builtin_memcpy(&s, &h, 2);
  return s;
}

__device__ inline float wred_sum(float v) {
#pragma unroll
  for (int m = 32; m > 0; m >>= 1) v += __shfl_xor(v, m, 64);
  return v;
}
__device__ inline float wred_max(float v) {
#pragma unroll
  for (int m = 32; m > 0; m >>= 1) v = fmaxf(v, __shfl_xor(v, m, 64));
  return v;
}

// async global->LDS, 16B per lane. LDS dest is wave-uniform base + lane*16.
__device__ inline void gld16(const short* g, short* lds_base) {
  __builtin_amdgcn_global_load_lds(
      (const __attribute__((address_space(1))) void*)g,
      (__attribute__((address_space(3))) void*)lds_base, 16, 0, 0);
}

// ---------------- LayerNorm: fp32 in -> bf16 out ----------------
__global__ __launch_bounds__(256) void ln_kernel(const float* __restrict__ x,
                                                 const float* __restrict__ g,
                                                 const float* __restrict__ b,
                                                 short* __restrict__ out) {
  const int row = blockIdx.x;
  const int tid = threadIdx.x;
  f32x4 v = *reinterpret_cast<const f32x4*>(x + (size_t)row * Dm + tid * 4);
  float s1 = v.x + v.y + v.z + v.w;
  float s2 = v.x * v.x + v.y * v.y + v.z * v.z + v.w * v.w;
  s1 = wred_sum(s1);
  s2 = wred_sum(s2);
  __shared__ float t1[4], t2[4];
  if ((tid & 63) == 0) { t1[tid >> 6] = s1; t2[tid >> 6] = s2; }
  __syncthreads();
  s1 = t1[0] + t1[1] + t1[2] + t1[3];
  s2 = t2[0] + t2[1] + t2[2] + t2[3];
  const float mean = s1 * (1.0f / Dm);
  const float var = s2 * (1.0f / Dm) - mean * mean;
  const float rstd = rsqrtf(var + EPSV);
  f32x4 gv = *reinterpret_cast<const f32x4*>(g + tid * 4);
  f32x4 bv = *reinterpret_cast<const f32x4*>(b + tid * 4);
  s16x4 o;
#pragma unroll
  for (int j = 0; j < 4; ++j)
    o[j] = f2bf((v[j] - mean) * rstd * gv[j] + bv[j]);
  *reinterpret_cast<s16x4*>(out + (size_t)row * Dm + tid * 4) = o;
}

// ------------- RoPE on q,k (fp32 qkv) -> bf16 q,k ; v -> bf16 V^T -------------
__global__ __launch_bounds__(256) void rope_kernel(const float* __restrict__ qkv,
                                                   const float* __restrict__ cosb,
                                                   const float* __restrict__ sinb,
                                                   short* __restrict__ qb,
                                                   short* __restrict__ kb,
                                                   short* __restrict__ vT) {
  const int s = blockIdx.x;
  const int tid = threadIdx.x;
  const float* rowq = qkv + (size_t)s * 3 * Dm;
#pragma unroll
  for (int it = 0; it < 4; ++it) {
    const int i = tid + it * 256;
    const int d = i & 63;
    const float c = cosb[(size_t)s * HDm + d];
    const float sn = sinb[(size_t)s * HDm + d];
    const int pi = (d < 32) ? i + 32 : i - 32;
    const float sgn = (d < 32) ? -1.0f : 1.0f;
    const float qv = rowq[i], qp = rowq[pi];
    qb[(size_t)s * Dm + i] = f2bf(qv * c + sgn * qp * sn);
    const float kv = rowq[Dm + i], kp = rowq[Dm + pi];
    kb[(size_t)s * Dm + i] = f2bf(kv * c + sgn * kp * sn);
    vT[(size_t)i * Sn + s] = f2bf(rowq[2 * Dm + i]);
  }
}

// -------- softmax over 512-length rows; fp32 in -> compact bf16 probs --------
__global__ __launch_bounds__(128) void softmax_kernel(const float* __restrict__ scores,
                                                      short* __restrict__ probs) {
  const size_t rowoff = ((size_t)blockIdx.y * SEG + blockIdx.x) * SEG;
  const float* rp = scores + rowoff;
  const int tid = threadIdx.x;
  f32x4 v = *reinterpret_cast<const f32x4*>(rp + tid * 4);
  float mx = fmaxf(fmaxf(v.x, v.y), fmaxf(v.z, v.w));
  mx = wred_max(mx);
  __shared__ float rmax[2], rsum[2];
  if ((tid & 63) == 0) rmax[tid >> 6] = mx;
  __syncthreads();
  mx = fmaxf(rmax[0], rmax[1]);
  f32x4 e;
#pragma unroll
  for (int j = 0; j < 4; ++j) e[j] = __expf(v[j] - mx);
  float sm = e.x + e.y + e.z + e.w;
  sm = wred_sum(sm);
  if ((tid & 63) == 0) rsum[tid >> 6] = sm;
  __syncthreads();
  const float inv = 1.0f / (rsum[0] + rsum[1]);
  s16x4 o;
#pragma unroll
  for (int j = 0; j < 4; ++j) o[j] = f2bf(e[j] * inv);
  *reinterpret_cast<s16x4*>(probs + rowoff + tid * 4) = o;
}

// -------- weight transpose + convert: W (K x N fp32) -> Wt (N x K bf16) --------
__global__ __launch_bounds__(256) void wt_kernel(const float* __restrict__ W,
                                                 short* __restrict__ Wt,
                                                 int K, int N) {
  __shared__ float t[32][33];
  const int n0 = blockIdx.x * 32, k0 = blockIdx.y * 32;
  const int tx = threadIdx.x & 31, ty = threadIdx.x >> 5;  // ty 0..7
#pragma unroll
  for (int r = 0; r < 32; r += 8)
    t[r + ty][tx] = W[(size_t)(k0 + r + ty) * N + n0 + tx];
  __syncthreads();
#pragma unroll
  for (int r = 0; r < 32; r += 8)
    Wt[(size_t)(n0 + r + ty) * K + k0 + tx] = f2bf(t[tx][r + ty]);
}

// ---------------- GEMM (m97 structure): C = A (MxK) * Bt^T (Bt is NxK) --------
// BM=128 fixed, BK=64, 256 threads (4 waves). global_load_lds staging, linear LDS.
// MODE 0: dense. MODE 1: QK^T batched (z=seg+4*head). MODE 2: PV batched.
// All tile dims must divide exactly (no guards).
struct GemmArgs {
  const short* A; int lda;
  const short* B; int ldb;
  void* C; int ldc;
  int M, N, K;
  const float* bias;
  const float* res; int ldres;
  float scale;
};

template <int BN, int MODE, int OBF16, int BIAS, int RES, int GELU>
__global__ __launch_bounds__(256) void gemm2(GemmArgs p) {
  constexpr int WN = BN / 64;        // waves along N: 2 (BN=128) or 1 (BN=64)
  constexpr int WM = 4 / WN;         // waves along M: 2 or 4
  constexpr int WRS = 128 / WM;      // rows per wave: 64 or 32
  constexpr int FI = WRS / 16;       // 4 or 2
  constexpr int FJ = 4;              // 64 cols per wave always
  const int z = blockIdx.z;
  const short* A = p.A;
  const short* B = p.B;
  char* Cb = (char*)p.C;
  if (MODE == 1) {
    const int seg = z & 3, hh = z >> 2;
    A += (size_t)(seg * SEG) * p.lda + hh * HDm;
    B += (size_t)(seg * SEG) * p.ldb + hh * HDm;
    Cb += (size_t)z * SEG * SEG * 4;
  } else if (MODE == 2) {
    const int seg = z & 3, hh = z >> 2;
    A += (size_t)z * SEG * SEG;                    // compact probs, lda=512
    B += (size_t)(hh * HDm) * p.ldb + seg * SEG;   // vT slice
    Cb += ((size_t)seg * SEG * Dm + (size_t)hh * HDm) * 2;
  }
  __shared__ short As[128 * 64];
  __shared__ short Bs[BN * 64];
  const int tid = threadIdx.x;
  const int lane = tid & 63;
  const int wave = tid >> 6;
  const int tileM = blockIdx.y * 128;
  const int tileN = blockIdx.x * BN;
  const int l15 = lane & 15;
  const int lg = lane >> 4;
  const int wr = (wave / WN) * WRS;
  const int wc = (wave % WN) * 64;
  const int srow = lane >> 3;          // 0..7
  const int scol = (lane & 7) * 8;     // shorts

  f32x4 acc[FI][FJ] = {};

  const short* Ag = A + (size_t)(tileM + wave * 8 + srow) * p.lda + scol;
  const short* Bg = B + (size_t)(tileN + wave * 8 + srow) * p.ldb + scol;

  const int nkt = p.K >> 6;
  for (int kt = 0; kt < nkt; ++kt) {
    const int k0 = kt * 64;
#pragma unroll
    for (int j = 0; j < 4; ++j)
      gld16(Ag + (size_t)(j * 32) * p.lda + k0, &As[(j * 32 + wave * 8) * 64]);
#pragma unroll
    for (int j = 0; j < BN / 32; ++j)
      gld16(Bg + (size_t)(j * 32) * p.ldb + k0, &Bs[(j * 32 + wave * 8) * 64]);
    __syncthreads();
#pragma unroll
    for (int kk = 0; kk < 64; kk += 32) {
      s16x8 af[FI], bfr[FJ];
#pragma unroll
      for (int f = 0; f < FI; ++f)
        af[f] = *reinterpret_cast<const s16x8*>(
            &As[(wr + f * 16 + l15) * 64 + kk + lg * 8]);
#pragma unroll
      for (int f = 0; f < FJ; ++f)
        bfr[f] = *reinterpret_cast<const s16x8*>(
            &Bs[(wc + f * 16 + l15) * 64 + kk + lg * 8]);
#pragma unroll
      for (int fi = 0; fi < FI; ++fi)
#pragma unroll
        for (int fj = 0; fj < FJ; ++fj)
          acc[fi][fj] = __builtin_amdgcn_mfma_f32_16x16x32_bf16(
              af[fi], bfr[fj], acc[fi][fj], 0, 0, 0);
    }
    __syncthreads();
  }

#pragma unroll
  for (int fi = 0; fi < FI; ++fi) {
#pragma unroll
    for (int fj = 0; fj < FJ; ++fj) {
#pragma unroll
      for (int r = 0; r < 4; ++r) {
        const int row = tileM + wr + fi * 16 + lg * 4 + r;
        const int col = tileN + wc + fj * 16 + l15;
        float v = acc[fi][fj][r] * p.scale;
        if (BIAS) v += p.bias[col];
        if (GELU) v = 0.5f * v * (1.0f + erff(v * 0.70710678118654752f));
        if (RES) v += p.res[(size_t)row * p.ldres + col];
        if (OBF16)
          reinterpret_cast<short*>(Cb)[(size_t)row * p.ldc + col] = f2bf(v);
        else
          reinterpret_cast<float*>(Cb)[(size_t)row * p.ldc + col] = v;
      }
    }
  }
}

extern "C" void kernel_launch(void* const* d_in, const int* in_sizes, int n_in,
                              void* d_out, int out_size, void* d_ws, size_t ws_size,
                              hipStream_t stream) {
  const float* x0 = (const float*)d_in[0];
  const float* cosb = (const float*)d_in[2];
  const float* sinb = (const float*)d_in[3];
  const float* ln1_g = (const float*)d_in[4];
  const float* ln1_b = (const float*)d_in[5];
  const float* qkv_w = (const float*)d_in[6];
  const float* qkv_b = (const float*)d_in[7];
  const float* proj_w = (const float*)d_in[8];
  const float* proj_b = (const float*)d_in[9];
  const float* ln2_g = (const float*)d_in[10];
  const float* ln2_b = (const float*)d_in[11];
  const float* fc1_w = (const float*)d_in[12];
  const float* fc1_b = (const float*)d_in[13];
  const float* fc2_w = (const float*)d_in[14];
  const float* fc2_b = (const float*)d_in[15];

  char* ws = (char*)d_ws;
  size_t off = 0;
  auto alloc = [&](size_t bytes) {
    void* p = ws + off;
    off += (bytes + 255) & ~(size_t)255;
    return p;
  };
  short* wqkvT = (short*)alloc((size_t)2 * 3072 * 1024 * 2);
  short* wprojT = (short*)alloc((size_t)2 * 1024 * 1024 * 2);
  short* wfc1T = (short*)alloc((size_t)2 * 4096 * 1024 * 2);
  short* wfc2T = (short*)alloc((size_t)2 * 1024 * 4096 * 2);
  float* xbuf = (float*)alloc((size_t)Sn * Dm * 4);
  short* hbuf = (short*)alloc((size_t)Sn * Dm * 2);
  // qkv (fp32, 25.2MB) is dead after rope; probs (bf16, 33.6MB) aliases it.
  float* qkv = (float*)alloc((size_t)64 * SEG * SEG * 2);  // max(qkv, probs)
  short* probs = (short*)qkv;
  short* qb = (short*)alloc((size_t)Sn * Dm * 2);
  short* kb = (short*)alloc((size_t)Sn * Dm * 2);
  short* vT = (short*)alloc((size_t)Sn * Dm * 2);
  float* scores = (float*)alloc((size_t)64 * SEG * SEG * 4);
  short* ao = (short*)alloc((size_t)Sn * Dm * 2);
  short* ffn = (short*)alloc((size_t)Sn * FFm * 2);
  (void)ws_size; (void)in_sizes; (void)n_in; (void)out_size;

  // weight transpose+convert (per call; stateless)
  for (int i = 0; i < 2; ++i) {
    wt_kernel<<<dim3(96, 32), 256, 0, stream>>>(
        qkv_w + (size_t)i * Dm * 3072, wqkvT + (size_t)i * 3072 * Dm, Dm, 3072);
    wt_kernel<<<dim3(32, 32), 256, 0, stream>>>(
        proj_w + (size_t)i * Dm * Dm, wprojT + (size_t)i * Dm * Dm, Dm, Dm);
    wt_kernel<<<dim3(128, 32), 256, 0, stream>>>(
        fc1_w + (size_t)i * Dm * FFm, wfc1T + (size_t)i * FFm * Dm, Dm, FFm);
    wt_kernel<<<dim3(32, 128), 256, 0, stream>>>(
        fc2_w + (size_t)i * FFm * Dm, wfc2T + (size_t)i * Dm * FFm, FFm, Dm);
  }

  for (int i = 0; i < 2; ++i) {
    const float* xin = i ? (const float*)xbuf : x0;

    ln_kernel<<<dim3(Sn), 256, 0, stream>>>(xin, ln1_g + i * Dm, ln1_b + i * Dm, hbuf);

    {  // qkv = h @ Wqkv + b  (fp32 out)
      GemmArgs p = {};
      p.A = hbuf; p.lda = Dm;
      p.B = wqkvT + (size_t)i * 3072 * Dm; p.ldb = Dm;
      p.C = qkv; p.ldc = 3 * Dm;
      p.M = Sn; p.N = 3 * Dm; p.K = Dm;
      p.bias = qkv_b + i * 3 * Dm; p.scale = 1.0f;
      gemm2<128, 0, 0, 1, 0, 0><<<dim3(24, 16, 1), 256, 0, stream>>>(p);
    }

    rope_kernel<<<dim3(Sn), 256, 0, stream>>>(qkv, cosb, sinb, qb, kb, vT);

    {  // scores = scale * q @ k^T  per (head, seg)  (fp32 out)
      GemmArgs p = {};
      p.A = qb; p.lda = Dm;
      p.B = kb; p.ldb = Dm;
      p.C = scores; p.ldc = SEG;
      p.M = SEG; p.N = SEG; p.K = HDm;
      p.scale = 0.125f;
      gemm2<128, 1, 0, 0, 0, 0><<<dim3(4, 4, 64), 256, 0, stream>>>(p);
    }

    softmax_kernel<<<dim3(SEG, 64), 128, 0, stream>>>(scores, probs);

    {  // ao = probs @ V  per (head, seg)  (bf16 out)
      GemmArgs p = {};
      p.A = probs; p.lda = SEG;
      p.B = vT; p.ldb = Sn;
      p.C = ao; p.ldc = Dm;
      p.M = SEG; p.N = HDm; p.K = SEG;
      p.scale = 1.0f;
      gemm2<64, 2, 1, 0, 0, 0><<<dim3(1, 4, 64), 256, 0, stream>>>(p);
    }

    {  // x = xin + ao @ Wproj + b  (fp32 out)
      GemmArgs p = {};
      p.A = ao; p.lda = Dm;
      p.B = wprojT + (size_t)i * Dm * Dm; p.ldb = Dm;
      p.C = xbuf; p.ldc = Dm;
      p.M = Sn; p.N = Dm; p.K = Dm;
      p.bias = proj_b + i * Dm; p.res = xin; p.ldres = Dm; p.scale = 1.0f;
      gemm2<64, 0, 0, 1, 1, 0><<<dim3(16, 16, 1), 256, 0, stream>>>(p);
    }

    ln_kernel<<<dim3(Sn), 256, 0, stream>>>(xbuf, ln2_g + i * Dm, ln2_b + i * Dm, hbuf);

    {  // ffn = gelu(h2 @ Wfc1 + b)  (bf16 out)
      GemmArgs p = {};
      p.A = hbuf; p.lda = Dm;
      p.B = wfc1T + (size_t)i * FFm * Dm; p.ldb = Dm;
      p.C = ffn; p.ldc = FFm;
      p.M = Sn; p.N = FFm; p.K = Dm;
      p.bias = fc1_b + i * FFm; p.scale = 1.0f;
      gemm2<128, 0, 1, 1, 0, 1><<<dim3(32, 16, 1), 256, 0, stream>>>(p);
    }

    {  // x = x + ffn @ Wfc2 + b  (fp32 out; layer 2 -> d_out)
      GemmArgs p = {};
      p.A = ffn; p.lda = FFm;
      p.B = wfc2T + (size_t)i * Dm * FFm; p.ldb = FFm;
      p.C = (i == 1) ? d_out : (void*)xbuf; p.ldc = Dm;
      p.M = Sn; p.N = Dm; p.K = FFm;
      p.bias = fc2_b + i * Dm; p.res = xbuf; p.ldres = Dm; p.scale = 1.0f;
      gemm2<64, 0, 0, 1, 1, 0><<<dim3(16, 16, 1), 256, 0, stream>>>(p);
    }
  }
}

// Round 3
// 450.515 us; speedup vs baseline: 1.7894x; 1.1753x over previous
//
#include <hip/hip_runtime.h>
#include <hip/hip_bf16.h>
#include <math.h>

#define Dm 1024
#define Hn 16
#define HDm 64
#define FFm 4096
#define Sn 2048
#define SEG 512
#define EPSV 1e-6f

typedef __attribute__((ext_vector_type(4))) float f32x4;
typedef __attribute__((ext_vector_type(8))) short s16x8;
typedef __attribute__((ext_vector_type(4))) short s16x4;

__device__ inline short f2bf(float f) {
  __hip_bfloat16 h = __float2bfloat16(f);
  short s;
  __builtin_memcpy(&s, &h, 2);
  return s;
}

__device__ inline float wred_sum(float v) {
#pragma unroll
  for (int m = 32; m > 0; m >>= 1) v += __shfl_xor(v, m, 64);
  return v;
}
__device__ inline float wred_max(float v) {
#pragma unroll
  for (int m = 32; m > 0; m >>= 1) v = fmaxf(v, __shfl_xor(v, m, 64));
  return v;
}

// async global->LDS, 16B per lane. LDS dest is wave-uniform base + lane*16.
__device__ inline void gld16(const short* g, short* lds_base) {
  __builtin_amdgcn_global_load_lds(
      (const __attribute__((address_space(1))) void*)g,
      (__attribute__((address_space(3))) void*)lds_base, 16, 0, 0);
}

// ---------------- LayerNorm: fp32 in -> bf16 out ----------------
__global__ __launch_bounds__(256) void ln_kernel(const float* __restrict__ x,
                                                 const float* __restrict__ g,
                                                 const float* __restrict__ b,
                                                 short* __restrict__ out) {
  const int row = blockIdx.x;
  const int tid = threadIdx.x;
  f32x4 v = *reinterpret_cast<const f32x4*>(x + (size_t)row * Dm + tid * 4);
  float s1 = v.x + v.y + v.z + v.w;
  float s2 = v.x * v.x + v.y * v.y + v.z * v.z + v.w * v.w;
  s1 = wred_sum(s1);
  s2 = wred_sum(s2);
  __shared__ float t1[4], t2[4];
  if ((tid & 63) == 0) { t1[tid >> 6] = s1; t2[tid >> 6] = s2; }
  __syncthreads();
  s1 = t1[0] + t1[1] + t1[2] + t1[3];
  s2 = t2[0] + t2[1] + t2[2] + t2[3];
  const float mean = s1 * (1.0f / Dm);
  const float var = s2 * (1.0f / Dm) - mean * mean;
  const float rstd = rsqrtf(var + EPSV);
  f32x4 gv = *reinterpret_cast<const f32x4*>(g + tid * 4);
  f32x4 bv = *reinterpret_cast<const f32x4*>(b + tid * 4);
  s16x4 o;
#pragma unroll
  for (int j = 0; j < 4; ++j)
    o[j] = f2bf((v[j] - mean) * rstd * gv[j] + bv[j]);
  *reinterpret_cast<s16x4*>(out + (size_t)row * Dm + tid * 4) = o;
}

// ------------- RoPE on q,k (fp32 qkv) -> bf16 q,k (coalesced) -------------
__global__ __launch_bounds__(256) void rope_kernel(const float* __restrict__ qkv,
                                                   const float* __restrict__ cosb,
                                                   const float* __restrict__ sinb,
                                                   short* __restrict__ qb,
                                                   short* __restrict__ kb) {
  const int s = blockIdx.x;
  const int tid = threadIdx.x;
  const float* rowq = qkv + (size_t)s * 3 * Dm;
#pragma unroll
  for (int it = 0; it < 4; ++it) {
    const int i = tid + it * 256;
    const int d = i & 63;
    const float c = cosb[(size_t)s * HDm + d];
    const float sn = sinb[(size_t)s * HDm + d];
    const int pi = (d < 32) ? i + 32 : i - 32;
    const float sgn = (d < 32) ? -1.0f : 1.0f;
    const float qv = rowq[i], qp = rowq[pi];
    qb[(size_t)s * Dm + i] = f2bf(qv * c + sgn * qp * sn);
    const float kv = rowq[Dm + i], kp = rowq[Dm + pi];
    kb[(size_t)s * Dm + i] = f2bf(kv * c + sgn * kp * sn);
  }
}

// -------- softmax over 512-length rows; fp32 in -> compact bf16 probs --------
__global__ __launch_bounds__(128) void softmax_kernel(const float* __restrict__ scores,
                                                      short* __restrict__ probs) {
  const size_t rowoff = ((size_t)blockIdx.y * SEG + blockIdx.x) * SEG;
  const float* rp = scores + rowoff;
  const int tid = threadIdx.x;
  f32x4 v = *reinterpret_cast<const f32x4*>(rp + tid * 4);
  float mx = fmaxf(fmaxf(v.x, v.y), fmaxf(v.z, v.w));
  mx = wred_max(mx);
  __shared__ float rmax[2], rsum[2];
  if ((tid & 63) == 0) rmax[tid >> 6] = mx;
  __syncthreads();
  mx = fmaxf(rmax[0], rmax[1]);
  f32x4 e;
#pragma unroll
  for (int j = 0; j < 4; ++j) e[j] = __expf(v[j] - mx);
  float sm = e.x + e.y + e.z + e.w;
  sm = wred_sum(sm);
  if ((tid & 63) == 0) rsum[tid >> 6] = sm;
  __syncthreads();
  const float inv = 1.0f / (rsum[0] + rsum[1]);
  s16x4 o;
#pragma unroll
  for (int j = 0; j < 4; ++j) o[j] = f2bf(e[j] * inv);
  *reinterpret_cast<s16x4*>(probs + rowoff + tid * 4) = o;
}

// ---- transpose + convert: W (K x N fp32, row stride ldw) -> Wt (N x K bf16) ----
__global__ __launch_bounds__(256) void wt_kernel(const float* __restrict__ W,
                                                 short* __restrict__ Wt,
                                                 int K, int N, int ldw) {
  __shared__ float t[32][33];
  const int n0 = blockIdx.x * 32, k0 = blockIdx.y * 32;
  const int tx = threadIdx.x & 31, ty = threadIdx.x >> 5;  // ty 0..7
#pragma unroll
  for (int r = 0; r < 32; r += 8)
    t[r + ty][tx] = W[(size_t)(k0 + r + ty) * ldw + n0 + tx];
  __syncthreads();
#pragma unroll
  for (int r = 0; r < 32; r += 8)
    Wt[(size_t)(n0 + r + ty) * K + k0 + tx] = f2bf(t[tx][r + ty]);
}

// ---------------- GEMM: C = A (MxK) * Bt^T (Bt is NxK) ----------------
// 2-phase double-buffered (prefetch next K-tile during compute), BK=64,
// 256 threads (4 waves). MODE 0: dense. MODE 1: QK^T batched. MODE 2: PV
// batched. MODE 3: dense split-K=2 (z=split, plain fp32 partial out).
struct GemmArgs {
  const short* A; int lda;
  const short* B; int ldb;
  void* C; int ldc;
  int M, N, K;
  const float* bias;
  const float* res; int ldres;
  float scale;
};

template <int BM, int BN, int MODE, int OBF16, int BIAS, int RES, int GELU>
__global__ __launch_bounds__(256) void gemm3(GemmArgs p) {
  constexpr int WN = (BN >= 128) ? 2 : ((BM >= 128) ? 1 : 2);
  constexpr int WM = 4 / WN;
  constexpr int FI = BM / WM / 16;
  constexpr int FJ = BN / WN / 16;
  const int z = blockIdx.z;
  const short* A = p.A;
  const short* B = p.B;
  char* Cb = (char*)p.C;
  int kbase = 0, nkt = p.K >> 6;
  if (MODE == 1) {
    const int seg = z & 3, hh = z >> 2;
    A += (size_t)(seg * SEG) * p.lda + hh * HDm;
    B += (size_t)(seg * SEG) * p.ldb + hh * HDm;
    Cb += (size_t)z * SEG * SEG * 4;
  } else if (MODE == 2) {
    const int seg = z & 3, hh = z >> 2;
    A += (size_t)z * SEG * SEG;                    // compact probs, lda=512
    B += (size_t)(hh * HDm) * p.ldb + seg * SEG;   // vT slice
    Cb += ((size_t)seg * SEG * Dm + (size_t)hh * HDm) * 2;
  } else if (MODE == 3) {
    kbase = z * (p.K >> 1);
    nkt = p.K >> 7;
    Cb += (size_t)z * p.M * p.N * 4;
  }
  __shared__ short As[2][BM * 64];
  __shared__ short Bs[2][BN * 64];
  const int tid = threadIdx.x;
  const int lane = tid & 63;
  const int wave = tid >> 6;
  const int tileM = blockIdx.y * BM;
  const int tileN = blockIdx.x * BN;
  const int l15 = lane & 15;
  const int lg = lane >> 4;
  const int wr = (wave / WN) * (BM / WM);
  const int wc = (wave % WN) * (BN / WN);
  const int srow = lane >> 3;          // 0..7
  const int scol = (lane & 7) * 8;     // shorts

  f32x4 acc[FI][FJ] = {};

  const short* Ag = A + (size_t)(tileM + wave * 8 + srow) * p.lda + scol + kbase;
  const short* Bg = B + (size_t)(tileN + wave * 8 + srow) * p.ldb + scol + kbase;

  auto stage = [&](int buf, int kt) {
    const int k0 = kt * 64;
#pragma unroll
    for (int j = 0; j < BM / 32; ++j)
      gld16(Ag + (size_t)(j * 32) * p.lda + k0, &As[buf][(j * 32 + wave * 8) * 64]);
#pragma unroll
    for (int j = 0; j < BN / 32; ++j)
      gld16(Bg + (size_t)(j * 32) * p.ldb + k0, &Bs[buf][(j * 32 + wave * 8) * 64]);
  };

  stage(0, 0);
  __syncthreads();
  int cur = 0;
  for (int kt = 0; kt < nkt; ++kt) {
    if (kt + 1 < nkt) stage(cur ^ 1, kt + 1);
    const short* Asc = As[cur];
    const short* Bsc = Bs[cur];
#pragma unroll
    for (int kk = 0; kk < 64; kk += 32) {
      s16x8 af[FI], bfr[FJ];
#pragma unroll
      for (int f = 0; f < FI; ++f)
        af[f] = *reinterpret_cast<const s16x8*>(
            &Asc[(wr + f * 16 + l15) * 64 + kk + lg * 8]);
#pragma unroll
      for (int f = 0; f < FJ; ++f)
        bfr[f] = *reinterpret_cast<const s16x8*>(
            &Bsc[(wc + f * 16 + l15) * 64 + kk + lg * 8]);
#pragma unroll
      for (int fi = 0; fi < FI; ++fi)
#pragma unroll
        for (int fj = 0; fj < FJ; ++fj)
          acc[fi][fj] = __builtin_amdgcn_mfma_f32_16x16x32_bf16(
              af[fi], bfr[fj], acc[fi][fj], 0, 0, 0);
    }
    __syncthreads();
    cur ^= 1;
  }

#pragma unroll
  for (int fi = 0; fi < FI; ++fi) {
#pragma unroll
    for (int fj = 0; fj < FJ; ++fj) {
#pragma unroll
      for (int r = 0; r < 4; ++r) {
        const int row = tileM + wr + fi * 16 + lg * 4 + r;
        const int col = tileN + wc + fj * 16 + l15;
        float v = acc[fi][fj][r] * p.scale;
        if (BIAS) v += p.bias[col];
        if (GELU) v = 0.5f * v * (1.0f + erff(v * 0.70710678118654752f));
        if (RES) v += p.res[(size_t)row * p.ldres + col];
        if (OBF16)
          reinterpret_cast<short*>(Cb)[(size_t)row * p.ldc + col] = f2bf(v);
        else
          reinterpret_cast<float*>(Cb)[(size_t)row * p.ldc + col] = v;
      }
    }
  }
}

// ---- split-K reduce: out = p0 + p1 + bias + res  (fp32) ----
__global__ __launch_bounds__(256) void fc2red(const float* __restrict__ pb,
                                              const float* __restrict__ bias,
                                              const float* __restrict__ res,
                                              float* __restrict__ out) {
  const size_t i = ((size_t)blockIdx.x * 256 + threadIdx.x) * 4;
  f32x4 a = *reinterpret_cast<const f32x4*>(pb + i);
  f32x4 b = *reinterpret_cast<const f32x4*>(pb + (size_t)Sn * Dm + i);
  f32x4 r = *reinterpret_cast<const f32x4*>(res + i);
  f32x4 bi = *reinterpret_cast<const f32x4*>(bias + (i & (Dm - 1)));
  f32x4 o = a + b + r + bi;
  *reinterpret_cast<f32x4*>(out + i) = o;
}

extern "C" void kernel_launch(void* const* d_in, const int* in_sizes, int n_in,
                              void* d_out, int out_size, void* d_ws, size_t ws_size,
                              hipStream_t stream) {
  const float* x0 = (const float*)d_in[0];
  const float* cosb = (const float*)d_in[2];
  const float* sinb = (const float*)d_in[3];
  const float* ln1_g = (const float*)d_in[4];
  const float* ln1_b = (const float*)d_in[5];
  const float* qkv_w = (const float*)d_in[6];
  const float* qkv_b = (const float*)d_in[7];
  const float* proj_w = (const float*)d_in[8];
  const float* proj_b = (const float*)d_in[9];
  const float* ln2_g = (const float*)d_in[10];
  const float* ln2_b = (const float*)d_in[11];
  const float* fc1_w = (const float*)d_in[12];
  const float* fc1_b = (const float*)d_in[13];
  const float* fc2_w = (const float*)d_in[14];
  const float* fc2_b = (const float*)d_in[15];

  char* ws = (char*)d_ws;
  size_t off = 0;
  auto alloc = [&](size_t bytes) {
    void* p = ws + off;
    off += (bytes + 255) & ~(size_t)255;
    return p;
  };
  short* wqkvT = (short*)alloc((size_t)2 * 3072 * 1024 * 2);
  short* wprojT = (short*)alloc((size_t)2 * 1024 * 1024 * 2);
  short* wfc1T = (short*)alloc((size_t)2 * 4096 * 1024 * 2);
  short* wfc2T = (short*)alloc((size_t)2 * 1024 * 4096 * 2);
  float* xbuf = (float*)alloc((size_t)Sn * Dm * 4);
  short* hbuf = (short*)alloc((size_t)Sn * Dm * 2);
  // qkv fp32 (25.2MB) dead after rope/vt; probs bf16 (33.6MB) aliases it.
  float* qkv = (float*)alloc((size_t)64 * SEG * SEG * 2);
  short* probs = (short*)qkv;
  short* qb = (short*)alloc((size_t)Sn * Dm * 2);
  short* kb = (short*)alloc((size_t)Sn * Dm * 2);
  short* vT = (short*)alloc((size_t)Sn * Dm * 2);
  // scores fp32 (67MB); dead by FC2 time -> split-K partials alias it.
  float* scores = (float*)alloc((size_t)64 * SEG * SEG * 4);
  float* pbuf = scores;
  short* ao = (short*)alloc((size_t)Sn * Dm * 2);
  short* ffn = (short*)alloc((size_t)Sn * FFm * 2);
  (void)ws_size; (void)in_sizes; (void)n_in; (void)out_size;

  // weight transpose+convert (per call; stateless)
  for (int i = 0; i < 2; ++i) {
    wt_kernel<<<dim3(96, 32), 256, 0, stream>>>(
        qkv_w + (size_t)i * Dm * 3072, wqkvT + (size_t)i * 3072 * Dm, Dm, 3072, 3072);
    wt_kernel<<<dim3(32, 32), 256, 0, stream>>>(
        proj_w + (size_t)i * Dm * Dm, wprojT + (size_t)i * Dm * Dm, Dm, Dm, Dm);
    wt_kernel<<<dim3(128, 32), 256, 0, stream>>>(
        fc1_w + (size_t)i * Dm * FFm, wfc1T + (size_t)i * FFm * Dm, Dm, FFm, FFm);
    wt_kernel<<<dim3(32, 128), 256, 0, stream>>>(
        fc2_w + (size_t)i * FFm * Dm, wfc2T + (size_t)i * Dm * FFm, FFm, Dm, Dm);
  }

  for (int i = 0; i < 2; ++i) {
    const float* xin = i ? (const float*)xbuf : x0;

    ln_kernel<<<dim3(Sn), 256, 0, stream>>>(xin, ln1_g + i * Dm, ln1_b + i * Dm, hbuf);

    {  // qkv = h @ Wqkv + b  (fp32 out)
      GemmArgs p = {};
      p.A = hbuf; p.lda = Dm;
      p.B = wqkvT + (size_t)i * 3072 * Dm; p.ldb = Dm;
      p.C = qkv; p.ldc = 3 * Dm;
      p.M = Sn; p.N = 3 * Dm; p.K = Dm;
      p.bias = qkv_b + i * 3 * Dm; p.scale = 1.0f;
      gemm3<64, 128, 0, 0, 1, 0, 0><<<dim3(24, 32, 1), 256, 0, stream>>>(p);
    }

    rope_kernel<<<dim3(Sn), 256, 0, stream>>>(qkv, cosb, sinb, qb, kb);
    // v (fp32 rows of qkv) -> vT bf16 (coalesced LDS-tiled transpose)
    wt_kernel<<<dim3(32, 64), 256, 0, stream>>>(qkv + 2 * Dm, vT, Sn, Dm, 3 * Dm);

    {  // scores = scale * q @ k^T  per (head, seg)  (fp32 out)
      GemmArgs p = {};
      p.A = qb; p.lda = Dm;
      p.B = kb; p.ldb = Dm;
      p.C = scores; p.ldc = SEG;
      p.M = SEG; p.N = SEG; p.K = HDm;
      p.scale = 0.125f;
      gemm3<64, 64, 1, 0, 0, 0, 0><<<dim3(8, 8, 64), 256, 0, stream>>>(p);
    }

    softmax_kernel<<<dim3(SEG, 64), 128, 0, stream>>>(scores, probs);

    {  // ao = probs @ V  per (head, seg)  (bf16 out)
      GemmArgs p = {};
      p.A = probs; p.lda = SEG;
      p.B = vT; p.ldb = Sn;
      p.C = ao; p.ldc = Dm;
      p.M = SEG; p.N = HDm; p.K = SEG;
      p.scale = 1.0f;
      gemm3<64, 64, 2, 1, 0, 0, 0><<<dim3(1, 8, 64), 256, 0, stream>>>(p);
    }

    {  // x = xin + ao @ Wproj + b  (fp32 out)
      GemmArgs p = {};
      p.A = ao; p.lda = Dm;
      p.B = wprojT + (size_t)i * Dm * Dm; p.ldb = Dm;
      p.C = xbuf; p.ldc = Dm;
      p.M = Sn; p.N = Dm; p.K = Dm;
      p.bias = proj_b + i * Dm; p.res = xin; p.ldres = Dm; p.scale = 1.0f;
      gemm3<64, 64, 0, 0, 1, 1, 0><<<dim3(16, 32, 1), 256, 0, stream>>>(p);
    }

    ln_kernel<<<dim3(Sn), 256, 0, stream>>>(xbuf, ln2_g + i * Dm, ln2_b + i * Dm, hbuf);

    {  // ffn = gelu(h2 @ Wfc1 + b)  (bf16 out)
      GemmArgs p = {};
      p.A = hbuf; p.lda = Dm;
      p.B = wfc1T + (size_t)i * FFm * Dm; p.ldb = Dm;
      p.C = ffn; p.ldc = FFm;
      p.M = Sn; p.N = FFm; p.K = Dm;
      p.bias = fc1_b + i * FFm; p.scale = 1.0f;
      gemm3<64, 128, 0, 1, 1, 0, 1><<<dim3(32, 32, 1), 256, 0, stream>>>(p);
    }

    {  // pbuf[z] = ffn @ Wfc2 (split-K=2 partials, fp32)
      GemmArgs p = {};
      p.A = ffn; p.lda = FFm;
      p.B = wfc2T + (size_t)i * Dm * FFm; p.ldb = FFm;
      p.C = pbuf; p.ldc = Dm;
      p.M = Sn; p.N = Dm; p.K = FFm;
      p.scale = 1.0f;
      gemm3<64, 64, 3, 0, 0, 0, 0><<<dim3(16, 32, 2), 256, 0, stream>>>(p);
    }
    {  // x = p0 + p1 + bias + xbuf  (layer 2 -> d_out)
      float* outp = (i == 1) ? (float*)d_out : xbuf;
      fc2red<<<dim3(Sn * Dm / 1024), 256, 0, stream>>>(pbuf, fc2_b + i * Dm, xbuf, outp);
    }
  }
}

// Round 4
// 401.194 us; speedup vs baseline: 2.0094x; 1.1229x over previous
//
#include <hip/hip_runtime.h>
#include <hip/hip_bf16.h>
#include <math.h>

#define Dm 1024
#define Hn 16
#define HDm 64
#define FFm 4096
#define Sn 2048
#define SEG 512
#define EPSV 1e-6f

typedef __attribute__((ext_vector_type(4))) float f32x4;
typedef __attribute__((ext_vector_type(8))) short s16x8;
typedef __attribute__((ext_vector_type(4))) short s16x4;

__device__ inline short f2bf(float f) {
  __hip_bfloat16 h = __float2bfloat16(f);
  short s;
  __builtin_memcpy(&s, &h, 2);
  return s;
}

__device__ inline float wred_sum(float v) {
#pragma unroll
  for (int m = 32; m > 0; m >>= 1) v += __shfl_xor(v, m, 64);
  return v;
}
__device__ inline float wred_max(float v) {
#pragma unroll
  for (int m = 32; m > 0; m >>= 1) v = fmaxf(v, __shfl_xor(v, m, 64));
  return v;
}

// async global->LDS, 16B per lane. LDS dest is wave-uniform base + lane*16.
__device__ inline void gld16(const short* g, short* lds_base) {
  __builtin_amdgcn_global_load_lds(
      (const __attribute__((address_space(1))) void*)g,
      (__attribute__((address_space(3))) void*)lds_base, 16, 0, 0);
}

// ---------------- LayerNorm: fp32 in -> bf16 out ----------------
__global__ __launch_bounds__(256) void ln_kernel(const float* __restrict__ x,
                                                 const float* __restrict__ g,
                                                 const float* __restrict__ b,
                                                 short* __restrict__ out) {
  const int row = blockIdx.x;
  const int tid = threadIdx.x;
  f32x4 v = *reinterpret_cast<const f32x4*>(x + (size_t)row * Dm + tid * 4);
  float s1 = v.x + v.y + v.z + v.w;
  float s2 = v.x * v.x + v.y * v.y + v.z * v.z + v.w * v.w;
  s1 = wred_sum(s1);
  s2 = wred_sum(s2);
  __shared__ float t1[4], t2[4];
  if ((tid & 63) == 0) { t1[tid >> 6] = s1; t2[tid >> 6] = s2; }
  __syncthreads();
  s1 = t1[0] + t1[1] + t1[2] + t1[3];
  s2 = t2[0] + t2[1] + t2[2] + t2[3];
  const float mean = s1 * (1.0f / Dm);
  const float var = s2 * (1.0f / Dm) - mean * mean;
  const float rstd = rsqrtf(var + EPSV);
  f32x4 gv = *reinterpret_cast<const f32x4*>(g + tid * 4);
  f32x4 bv = *reinterpret_cast<const f32x4*>(b + tid * 4);
  s16x4 o;
#pragma unroll
  for (int j = 0; j < 4; ++j)
    o[j] = f2bf((v[j] - mean) * rstd * gv[j] + bv[j]);
  *reinterpret_cast<s16x4*>(out + (size_t)row * Dm + tid * 4) = o;
}

// ------------- RoPE on q,k (fp32 qkv) -> bf16 q,k (coalesced) -------------
__global__ __launch_bounds__(256) void rope_kernel(const float* __restrict__ qkv,
                                                   const float* __restrict__ cosb,
                                                   const float* __restrict__ sinb,
                                                   short* __restrict__ qb,
                                                   short* __restrict__ kb) {
  const int s = blockIdx.x;
  const int tid = threadIdx.x;
  const float* rowq = qkv + (size_t)s * 3 * Dm;
#pragma unroll
  for (int it = 0; it < 4; ++it) {
    const int i = tid + it * 256;
    const int d = i & 63;
    const float c = cosb[(size_t)s * HDm + d];
    const float sn = sinb[(size_t)s * HDm + d];
    const int pi = (d < 32) ? i + 32 : i - 32;
    const float sgn = (d < 32) ? -1.0f : 1.0f;
    const float qv = rowq[i], qp = rowq[pi];
    qb[(size_t)s * Dm + i] = f2bf(qv * c + sgn * qp * sn);
    const float kv = rowq[Dm + i], kp = rowq[Dm + pi];
    kb[(size_t)s * Dm + i] = f2bf(kv * c + sgn * kp * sn);
  }
}

// -------- softmax over 512-length rows; fp32 in -> compact bf16 probs --------
__global__ __launch_bounds__(128) void softmax_kernel(const float* __restrict__ scores,
                                                      short* __restrict__ probs) {
  const size_t rowoff = ((size_t)blockIdx.y * SEG + blockIdx.x) * SEG;
  const float* rp = scores + rowoff;
  const int tid = threadIdx.x;
  f32x4 v = *reinterpret_cast<const f32x4*>(rp + tid * 4);
  float mx = fmaxf(fmaxf(v.x, v.y), fmaxf(v.z, v.w));
  mx = wred_max(mx);
  __shared__ float rmax[2], rsum[2];
  if ((tid & 63) == 0) rmax[tid >> 6] = mx;
  __syncthreads();
  mx = fmaxf(rmax[0], rmax[1]);
  f32x4 e;
#pragma unroll
  for (int j = 0; j < 4; ++j) e[j] = __expf(v[j] - mx);
  float sm = e.x + e.y + e.z + e.w;
  sm = wred_sum(sm);
  if ((tid & 63) == 0) rsum[tid >> 6] = sm;
  __syncthreads();
  const float inv = 1.0f / (rsum[0] + rsum[1]);
  s16x4 o;
#pragma unroll
  for (int j = 0; j < 4; ++j) o[j] = f2bf(e[j] * inv);
  *reinterpret_cast<s16x4*>(probs + rowoff + tid * 4) = o;
}

// ---- transpose + convert: W (K x N fp32, row stride ldw) -> Wt (N x K bf16) ----
__global__ __launch_bounds__(256) void wt_kernel(const float* __restrict__ W,
                                                 short* __restrict__ Wt,
                                                 int K, int N, int ldw) {
  __shared__ float t[32][33];
  const int n0 = blockIdx.x * 32, k0 = blockIdx.y * 32;
  const int tx = threadIdx.x & 31, ty = threadIdx.x >> 5;  // ty 0..7
#pragma unroll
  for (int r = 0; r < 32; r += 8)
    t[r + ty][tx] = W[(size_t)(k0 + r + ty) * ldw + n0 + tx];
  __syncthreads();
#pragma unroll
  for (int r = 0; r < 32; r += 8)
    Wt[(size_t)(n0 + r + ty) * K + k0 + tx] = f2bf(t[tx][r + ty]);
}

// ---------------- GEMM: C = A (MxK) * Bt^T (Bt is NxK) ----------------
// m97 structure: single-buffered BK=64, 256 threads (4 waves), global_load_lds
// staging with XOR-swizzled SOURCE (linear LDS dest) + swizzled ds_read
// (conflict-free). MODE 0: dense. MODE 1: QK^T batched. MODE 2: PV batched.
// MODE 3: dense split-K (z=split, fp32 partial out).
struct GemmArgs {
  const short* A; int lda;
  const short* B; int ldb;
  void* C; int ldc;
  int M, N, K;
  const float* bias;
  const float* res; int ldres;
  float scale;
};

template <int BM, int BN, int SPLIT, int MODE, int OBF16, int BIAS, int RES, int GELU>
__global__ __launch_bounds__(256) void gemm4(GemmArgs p) {
  constexpr int WN = 2;
  constexpr int WM = 2;
  constexpr int FI = BM / WM / 16;   // 4 (BM=128) or 2 (BM=64)
  constexpr int FJ = BN / WN / 16;
  const int z = blockIdx.z;
  const short* A = p.A;
  const short* B = p.B;
  char* Cb = (char*)p.C;
  int kbase = 0, nkt = p.K >> 6;
  if (MODE == 1) {
    const int seg = z & 3, hh = z >> 2;
    A += (size_t)(seg * SEG) * p.lda + hh * HDm;
    B += (size_t)(seg * SEG) * p.ldb + hh * HDm;
    Cb += (size_t)z * SEG * SEG * 4;
  } else if (MODE == 2) {
    const int seg = z & 3, hh = z >> 2;
    A += (size_t)z * SEG * SEG;                    // compact probs, lda=512
    B += (size_t)(hh * HDm) * p.ldb + seg * SEG;   // vT slice
    Cb += ((size_t)seg * SEG * Dm + (size_t)hh * HDm) * 2;
  } else if (MODE == 3) {
    kbase = z * (p.K / SPLIT);
    nkt = (p.K / SPLIT) >> 6;
    Cb += (size_t)z * p.M * p.N * 4;
  }
  __shared__ short As[BM * 64];
  __shared__ short Bs[BN * 64];
  const int tid = threadIdx.x;
  const int lane = tid & 63;
  const int wave = tid >> 6;
  const int tileM = blockIdx.y * BM;
  const int tileN = blockIdx.x * BN;
  const int l15 = lane & 15;
  const int lg = lane >> 4;
  const int rx = l15 & 7;              // read-side swizzle key
  const int wr = (wave / WN) * (BM / WM);
  const int wc = (wave % WN) * (BN / WN);
  const int srow = lane >> 3;                      // 0..7
  const int scol = ((lane & 7) ^ srow) * 8;        // swizzled source chunk

  f32x4 acc[FI][FJ] = {};

  const short* Ag = A + (size_t)(tileM + wave * 8 + srow) * p.lda + scol + kbase;
  const short* Bg = B + (size_t)(tileN + wave * 8 + srow) * p.ldb + scol + kbase;

  for (int kt = 0; kt < nkt; ++kt) {
    const int k0 = kt * 64;
#pragma unroll
    for (int j = 0; j < BM / 32; ++j)
      gld16(Ag + (size_t)(j * 32) * p.lda + k0, &As[(j * 32 + wave * 8) * 64]);
#pragma unroll
    for (int j = 0; j < BN / 32; ++j)
      gld16(Bg + (size_t)(j * 32) * p.ldb + k0, &Bs[(j * 32 + wave * 8) * 64]);
    __syncthreads();
#pragma unroll
    for (int kk = 0; kk < 64; kk += 32) {
      const int kkc = kk >> 3;  // chunk base: 0 or 4
      s16x8 af[FI], bfr[FJ];
#pragma unroll
      for (int f = 0; f < FI; ++f)
        af[f] = *reinterpret_cast<const s16x8*>(
            &As[(wr + f * 16 + l15) * 64 + (((lg + kkc) ^ rx) << 3)]);
#pragma unroll
      for (int f = 0; f < FJ; ++f)
        bfr[f] = *reinterpret_cast<const s16x8*>(
            &Bs[(wc + f * 16 + l15) * 64 + (((lg + kkc) ^ rx) << 3)]);
#pragma unroll
      for (int fi = 0; fi < FI; ++fi)
#pragma unroll
        for (int fj = 0; fj < FJ; ++fj)
          acc[fi][fj] = __builtin_amdgcn_mfma_f32_16x16x32_bf16(
              af[fi], bfr[fj], acc[fi][fj], 0, 0, 0);
    }
    __syncthreads();
  }

#pragma unroll
  for (int fi = 0; fi < FI; ++fi) {
#pragma unroll
    for (int fj = 0; fj < FJ; ++fj) {
#pragma unroll
      for (int r = 0; r < 4; ++r) {
        const int row = tileM + wr + fi * 16 + lg * 4 + r;
        const int col = tileN + wc + fj * 16 + l15;
        float v = acc[fi][fj][r] * p.scale;
        if (BIAS) v += p.bias[col];
        if (GELU) v = 0.5f * v * (1.0f + erff(v * 0.70710678118654752f));
        if (RES) v += p.res[(size_t)row * p.ldres + col];
        if (OBF16)
          reinterpret_cast<short*>(Cb)[(size_t)row * p.ldc + col] = f2bf(v);
        else
          reinterpret_cast<float*>(Cb)[(size_t)row * p.ldc + col] = v;
      }
    }
  }
}

// ---- split-K reduce: out = sum(partials) + bias + res  (fp32) ----
template <int SPLIT>
__global__ __launch_bounds__(256) void fcred(const float* __restrict__ pb,
                                             const float* __restrict__ bias,
                                             const float* __restrict__ res,
                                             float* __restrict__ out) {
  const size_t i = ((size_t)blockIdx.x * 256 + threadIdx.x) * 4;
  f32x4 o = *reinterpret_cast<const f32x4*>(res + i);
  f32x4 bi = *reinterpret_cast<const f32x4*>(bias + (i & (Dm - 1)));
  o += bi;
#pragma unroll
  for (int s = 0; s < SPLIT; ++s)
    o += *reinterpret_cast<const f32x4*>(pb + (size_t)s * Sn * Dm + i);
  *reinterpret_cast<f32x4*>(out + i) = o;
}

extern "C" void kernel_launch(void* const* d_in, const int* in_sizes, int n_in,
                              void* d_out, int out_size, void* d_ws, size_t ws_size,
                              hipStream_t stream) {
  const float* x0 = (const float*)d_in[0];
  const float* cosb = (const float*)d_in[2];
  const float* sinb = (const float*)d_in[3];
  const float* ln1_g = (const float*)d_in[4];
  const float* ln1_b = (const float*)d_in[5];
  const float* qkv_w = (const float*)d_in[6];
  const float* qkv_b = (const float*)d_in[7];
  const float* proj_w = (const float*)d_in[8];
  const float* proj_b = (const float*)d_in[9];
  const float* ln2_g = (const float*)d_in[10];
  const float* ln2_b = (const float*)d_in[11];
  const float* fc1_w = (const float*)d_in[12];
  const float* fc1_b = (const float*)d_in[13];
  const float* fc2_w = (const float*)d_in[14];
  const float* fc2_b = (const float*)d_in[15];

  char* ws = (char*)d_ws;
  size_t off = 0;
  auto alloc = [&](size_t bytes) {
    void* p = ws + off;
    off += (bytes + 255) & ~(size_t)255;
    return p;
  };
  short* wqkvT = (short*)alloc((size_t)2 * 3072 * 1024 * 2);
  short* wprojT = (short*)alloc((size_t)2 * 1024 * 1024 * 2);
  short* wfc1T = (short*)alloc((size_t)2 * 4096 * 1024 * 2);
  short* wfc2T = (short*)alloc((size_t)2 * 1024 * 4096 * 2);
  float* xbuf = (float*)alloc((size_t)Sn * Dm * 4);
  short* hbuf = (short*)alloc((size_t)Sn * Dm * 2);
  // qkv fp32 (25.2MB) dead after rope/vt; probs bf16 (33.6MB) aliases it.
  float* qkv = (float*)alloc((size_t)64 * SEG * SEG * 2);
  short* probs = (short*)qkv;
  short* qb = (short*)alloc((size_t)Sn * Dm * 2);
  short* kb = (short*)alloc((size_t)Sn * Dm * 2);
  short* vT = (short*)alloc((size_t)Sn * Dm * 2);
  // scores fp32 (67MB); dead by FC2 time -> split-K partials (33.6MB) alias it.
  float* scores = (float*)alloc((size_t)64 * SEG * SEG * 4);
  float* pbuf = scores;
  short* ao = (short*)alloc((size_t)Sn * Dm * 2);
  short* ffn = (short*)alloc((size_t)Sn * FFm * 2);
  (void)ws_size; (void)in_sizes; (void)n_in; (void)out_size;

  // weight transpose+convert (per call; stateless)
  for (int i = 0; i < 2; ++i) {
    wt_kernel<<<dim3(96, 32), 256, 0, stream>>>(
        qkv_w + (size_t)i * Dm * 3072, wqkvT + (size_t)i * 3072 * Dm, Dm, 3072, 3072);
    wt_kernel<<<dim3(32, 32), 256, 0, stream>>>(
        proj_w + (size_t)i * Dm * Dm, wprojT + (size_t)i * Dm * Dm, Dm, Dm, Dm);
    wt_kernel<<<dim3(128, 32), 256, 0, stream>>>(
        fc1_w + (size_t)i * Dm * FFm, wfc1T + (size_t)i * FFm * Dm, Dm, FFm, FFm);
    wt_kernel<<<dim3(32, 128), 256, 0, stream>>>(
        fc2_w + (size_t)i * FFm * Dm, wfc2T + (size_t)i * Dm * FFm, FFm, Dm, Dm);
  }

  for (int i = 0; i < 2; ++i) {
    const float* xin = i ? (const float*)xbuf : x0;

    ln_kernel<<<dim3(Sn), 256, 0, stream>>>(xin, ln1_g + i * Dm, ln1_b + i * Dm, hbuf);

    {  // qkv = h @ Wqkv + b  (fp32 out)
      GemmArgs p = {};
      p.A = hbuf; p.lda = Dm;
      p.B = wqkvT + (size_t)i * 3072 * Dm; p.ldb = Dm;
      p.C = qkv; p.ldc = 3 * Dm;
      p.M = Sn; p.N = 3 * Dm; p.K = Dm;
      p.bias = qkv_b + i * 3 * Dm; p.scale = 1.0f;
      gemm4<128, 128, 1, 0, 0, 1, 0, 0><<<dim3(24, 16, 1), 256, 0, stream>>>(p);
    }

    rope_kernel<<<dim3(Sn), 256, 0, stream>>>(qkv, cosb, sinb, qb, kb);
    // v (fp32 rows of qkv) -> vT bf16 (coalesced LDS-tiled transpose)
    wt_kernel<<<dim3(32, 64), 256, 0, stream>>>(qkv + 2 * Dm, vT, Sn, Dm, 3 * Dm);

    {  // scores = scale * q @ k^T  per (head, seg)  (fp32 out)
      GemmArgs p = {};
      p.A = qb; p.lda = Dm;
      p.B = kb; p.ldb = Dm;
      p.C = scores; p.ldc = SEG;
      p.M = SEG; p.N = SEG; p.K = HDm;
      p.scale = 0.125f;
      gemm4<128, 128, 1, 1, 0, 0, 0, 0><<<dim3(4, 4, 64), 256, 0, stream>>>(p);
    }

    softmax_kernel<<<dim3(SEG, 64), 128, 0, stream>>>(scores, probs);

    {  // ao = probs @ V  per (head, seg)  (bf16 out)
      GemmArgs p = {};
      p.A = probs; p.lda = SEG;
      p.B = vT; p.ldb = Sn;
      p.C = ao; p.ldc = Dm;
      p.M = SEG; p.N = HDm; p.K = SEG;
      p.scale = 1.0f;
      gemm4<64, 64, 1, 2, 1, 0, 0, 0><<<dim3(1, 8, 64), 256, 0, stream>>>(p);
    }

    {  // x = xin + ao @ Wproj + b  (fp32 out)
      GemmArgs p = {};
      p.A = ao; p.lda = Dm;
      p.B = wprojT + (size_t)i * Dm * Dm; p.ldb = Dm;
      p.C = xbuf; p.ldc = Dm;
      p.M = Sn; p.N = Dm; p.K = Dm;
      p.bias = proj_b + i * Dm; p.res = xin; p.ldres = Dm; p.scale = 1.0f;
      gemm4<64, 64, 1, 0, 0, 1, 1, 0><<<dim3(16, 32, 1), 256, 0, stream>>>(p);
    }

    ln_kernel<<<dim3(Sn), 256, 0, stream>>>(xbuf, ln2_g + i * Dm, ln2_b + i * Dm, hbuf);

    {  // ffn = gelu(h2 @ Wfc1 + b)  (bf16 out)
      GemmArgs p = {};
      p.A = hbuf; p.lda = Dm;
      p.B = wfc1T + (size_t)i * FFm * Dm; p.ldb = Dm;
      p.C = ffn; p.ldc = FFm;
      p.M = Sn; p.N = FFm; p.K = Dm;
      p.bias = fc1_b + i * FFm; p.scale = 1.0f;
      gemm4<128, 128, 1, 0, 1, 1, 0, 1><<<dim3(32, 16, 1), 256, 0, stream>>>(p);
    }

    {  // pbuf[z] = ffn @ Wfc2 (split-K=4 partials, fp32)
      GemmArgs p = {};
      p.A = ffn; p.lda = FFm;
      p.B = wfc2T + (size_t)i * Dm * FFm; p.ldb = FFm;
      p.C = pbuf; p.ldc = Dm;
      p.M = Sn; p.N = Dm; p.K = FFm;
      p.scale = 1.0f;
      gemm4<128, 128, 4, 3, 0, 0, 0, 0><<<dim3(8, 16, 4), 256, 0, stream>>>(p);
    }
    {  // x = sum(partials) + bias + xbuf  (layer 2 -> d_out)
      float* outp = (i == 1) ? (float*)d_out : xbuf;
      fcred<4><<<dim3(Sn * Dm / 1024), 256, 0, stream>>>(pbuf, fc2_b + i * Dm, xbuf, outp);
    }
  }
}

// Round 5
// 391.804 us; speedup vs baseline: 2.0575x; 1.0240x over previous
//
#include <hip/hip_runtime.h>
#include <hip/hip_bf16.h>
#include <math.h>

#define Dm 1024
#define Hn 16
#define HDm 64
#define FFm 4096
#define Sn 2048
#define SEG 512
#define EPSV 1e-6f

typedef __attribute__((ext_vector_type(4))) float f32x4;
typedef __attribute__((ext_vector_type(8))) short s16x8;
typedef __attribute__((ext_vector_type(4))) short s16x4;

__device__ inline short f2bf(float f) {
  __hip_bfloat16 h = __float2bfloat16(f);
  short s;
  __builtin_memcpy(&s, &h, 2);
  return s;
}

__device__ inline float wred_sum(float v) {
#pragma unroll
  for (int m = 32; m > 0; m >>= 1) v += __shfl_xor(v, m, 64);
  return v;
}
__device__ inline float wred_max(float v) {
#pragma unroll
  for (int m = 32; m > 0; m >>= 1) v = fmaxf(v, __shfl_xor(v, m, 64));
  return v;
}

// async global->LDS, 16B per lane. LDS dest is wave-uniform base + lane*16.
__device__ inline void gld16(const short* g, short* lds_base) {
  __builtin_amdgcn_global_load_lds(
      (const __attribute__((address_space(1))) void*)g,
      (__attribute__((address_space(3))) void*)lds_base, 16, 0, 0);
}

template <int N>
__device__ inline void waitv() {
  if constexpr (N == 0) asm volatile("s_waitcnt vmcnt(0)" ::: "memory");
  else if constexpr (N == 4) asm volatile("s_waitcnt vmcnt(4)" ::: "memory");
  else if constexpr (N == 6) asm volatile("s_waitcnt vmcnt(6)" ::: "memory");
  else if constexpr (N == 8) asm volatile("s_waitcnt vmcnt(8)" ::: "memory");
  else static_assert(N == -1, "unsupported vmcnt");
}

// ---------------- LayerNorm: fp32 in -> bf16 out ----------------
__global__ __launch_bounds__(256) void ln_kernel(const float* __restrict__ x,
                                                 const float* __restrict__ g,
                                                 const float* __restrict__ b,
                                                 short* __restrict__ out) {
  const int row = blockIdx.x;
  const int tid = threadIdx.x;
  f32x4 v = *reinterpret_cast<const f32x4*>(x + (size_t)row * Dm + tid * 4);
  float s1 = v.x + v.y + v.z + v.w;
  float s2 = v.x * v.x + v.y * v.y + v.z * v.z + v.w * v.w;
  s1 = wred_sum(s1);
  s2 = wred_sum(s2);
  __shared__ float t1[4], t2[4];
  if ((tid & 63) == 0) { t1[tid >> 6] = s1; t2[tid >> 6] = s2; }
  __syncthreads();
  s1 = t1[0] + t1[1] + t1[2] + t1[3];
  s2 = t2[0] + t2[1] + t2[2] + t2[3];
  const float mean = s1 * (1.0f / Dm);
  const float var = s2 * (1.0f / Dm) - mean * mean;
  const float rstd = rsqrtf(var + EPSV);
  f32x4 gv = *reinterpret_cast<const f32x4*>(g + tid * 4);
  f32x4 bv = *reinterpret_cast<const f32x4*>(b + tid * 4);
  s16x4 o;
#pragma unroll
  for (int j = 0; j < 4; ++j)
    o[j] = f2bf((v[j] - mean) * rstd * gv[j] + bv[j]);
  *reinterpret_cast<s16x4*>(out + (size_t)row * Dm + tid * 4) = o;
}

// -------- softmax over 512-length rows; fp32 in -> compact bf16 probs --------
__global__ __launch_bounds__(128) void softmax_kernel(const float* __restrict__ scores,
                                                      short* __restrict__ probs) {
  const size_t rowoff = ((size_t)blockIdx.y * SEG + blockIdx.x) * SEG;
  const float* rp = scores + rowoff;
  const int tid = threadIdx.x;
  f32x4 v = *reinterpret_cast<const f32x4*>(rp + tid * 4);
  float mx = fmaxf(fmaxf(v.x, v.y), fmaxf(v.z, v.w));
  mx = wred_max(mx);
  __shared__ float rmax[2], rsum[2];
  if ((tid & 63) == 0) rmax[tid >> 6] = mx;
  __syncthreads();
  mx = fmaxf(rmax[0], rmax[1]);
  f32x4 e;
#pragma unroll
  for (int j = 0; j < 4; ++j) e[j] = __expf(v[j] - mx);
  float sm = e.x + e.y + e.z + e.w;
  sm = wred_sum(sm);
  if ((tid & 63) == 0) rsum[tid >> 6] = sm;
  __syncthreads();
  const float inv = 1.0f / (rsum[0] + rsum[1]);
  s16x4 o;
#pragma unroll
  for (int j = 0; j < 4; ++j) o[j] = f2bf(e[j] * inv);
  *reinterpret_cast<s16x4*>(probs + rowoff + tid * 4) = o;
}

// ---- transpose + convert: W (K x N fp32, row stride ldw) -> Wt (N x K bf16) ----
__global__ __launch_bounds__(256) void wt_kernel(const float* __restrict__ W,
                                                 short* __restrict__ Wt,
                                                 int K, int N, int ldw) {
  __shared__ float t[32][33];
  const int n0 = blockIdx.x * 32, k0 = blockIdx.y * 32;
  const int tx = threadIdx.x & 31, ty = threadIdx.x >> 5;  // ty 0..7
#pragma unroll
  for (int r = 0; r < 32; r += 8)
    t[r + ty][tx] = W[(size_t)(k0 + r + ty) * ldw + n0 + tx];
  __syncthreads();
#pragma unroll
  for (int r = 0; r < 32; r += 8)
    Wt[(size_t)(n0 + r + ty) * K + k0 + tx] = f2bf(t[tx][r + ty]);
}

// ---- bf16 transpose: V (K x N bf16, row stride ldv) -> Vt (N x K bf16) ----
__global__ __launch_bounds__(256) void wtb_kernel(const short* __restrict__ V,
                                                  short* __restrict__ Vt,
                                                  int K, int N, int ldv) {
  __shared__ short t[32][34];
  const int n0 = blockIdx.x * 32, k0 = blockIdx.y * 32;
  const int tx = threadIdx.x & 31, ty = threadIdx.x >> 5;
#pragma unroll
  for (int r = 0; r < 32; r += 8)
    t[r + ty][tx] = V[(size_t)(k0 + r + ty) * ldv + n0 + tx];
  __syncthreads();
#pragma unroll
  for (int r = 0; r < 32; r += 8)
    Vt[(size_t)(n0 + r + ty) * K + k0 + tx] = t[tx][r + ty];
}

// ---------------- GEMM: C = A (MxK) * Bt^T (Bt is NxK) ----------------
// Counted-vmcnt double-buffered K-loop (T3+T4): stage(next) -> vmcnt(LOADS)
// (next tile's loads stay in flight across the barrier) -> raw s_barrier ->
// compute -> s_barrier. XOR-swizzled gld source + swizzled ds_read.
// MODE 0: dense. MODE 1: QK^T batched. MODE 2: PV batched.
// MODE 3: dense split-K (fp32 partials). MODE 4: dense + fused RoPE (bf16 out).
struct GemmArgs {
  const short* A; int lda;
  const short* B; int ldb;
  void* C; int ldc;
  int M, N, K;
  const float* bias;
  const float* res; int ldres;
  const float* cosb; const float* sinb;
  float scale;
};

template <int BM, int BN, int SPLIT, int MODE, int OBF16, int BIAS, int RES, int GELU>
__global__ __launch_bounds__(256) void gemm5(GemmArgs p) {
  constexpr int WN = 2;
  constexpr int WM = 2;
  constexpr int FI = BM / WM / 16;
  constexpr int FJ = BN / WN / 16;
  constexpr int LOADS = BM / 32 + BN / 32;
  const int z = blockIdx.z;
  const short* A = p.A;
  const short* B = p.B;
  char* Cb = (char*)p.C;
  int kbase = 0, nkt = p.K >> 6;
  if (MODE == 1) {
    const int seg = z & 3, hh = z >> 2;
    A += (size_t)(seg * SEG) * p.lda + hh * HDm;
    B += (size_t)(seg * SEG) * p.ldb + hh * HDm;
    Cb += (size_t)z * SEG * SEG * 4;
  } else if (MODE == 2) {
    const int seg = z & 3, hh = z >> 2;
    A += (size_t)z * SEG * SEG;                    // compact probs, lda=512
    B += (size_t)(hh * HDm) * p.ldb + seg * SEG;   // vT slice
    Cb += ((size_t)seg * SEG * Dm + (size_t)hh * HDm) * 2;
  } else if (MODE == 3) {
    kbase = z * (p.K / SPLIT);
    nkt = (p.K / SPLIT) >> 6;
    Cb += (size_t)z * p.M * p.N * 4;
  }
  __shared__ short As[2][BM * 64];
  __shared__ short Bs[2][BN * 64];
  const int tid = threadIdx.x;
  const int lane = tid & 63;
  const int wave = tid >> 6;
  const int tileM = blockIdx.y * BM;
  const int tileN = blockIdx.x * BN;
  const int l15 = lane & 15;
  const int lg = lane >> 4;
  const int rx = l15 & 7;              // read-side swizzle key
  const int wr = (wave / WN) * (BM / WM);
  const int wc = (wave % WN) * (BN / WN);
  const int srow = lane >> 3;                      // 0..7
  const int scol = ((lane & 7) ^ srow) * 8;        // swizzled source chunk

  f32x4 acc[FI][FJ] = {};

  const short* Ag = A + (size_t)(tileM + wave * 8 + srow) * p.lda + scol + kbase;
  const short* Bg = B + (size_t)(tileN + wave * 8 + srow) * p.ldb + scol + kbase;

  auto stage = [&](int buf, int kt) {
    const int k0 = kt * 64;
#pragma unroll
    for (int j = 0; j < BM / 32; ++j)
      gld16(Ag + (size_t)(j * 32) * p.lda + k0, &As[buf][(j * 32 + wave * 8) * 64]);
#pragma unroll
    for (int j = 0; j < BN / 32; ++j)
      gld16(Bg + (size_t)(j * 32) * p.ldb + k0, &Bs[buf][(j * 32 + wave * 8) * 64]);
  };

  stage(0, 0);
  int cur = 0;
  for (int kt = 0; kt < nkt; ++kt) {
    if (kt + 1 < nkt) {
      stage(cur ^ 1, kt + 1);
      waitv<LOADS>();      // wait current tile only; next stays in flight
    } else {
      waitv<0>();
    }
    __builtin_amdgcn_s_barrier();
    __builtin_amdgcn_sched_barrier(0);
    const short* Asc = As[cur];
    const short* Bsc = Bs[cur];
#pragma unroll
    for (int kk = 0; kk < 64; kk += 32) {
      const int kkc = kk >> 3;  // chunk base: 0 or 4
      s16x8 af[FI], bfr[FJ];
#pragma unroll
      for (int f = 0; f < FI; ++f)
        af[f] = *reinterpret_cast<const s16x8*>(
            &Asc[(wr + f * 16 + l15) * 64 + (((lg + kkc) ^ rx) << 3)]);
#pragma unroll
      for (int f = 0; f < FJ; ++f)
        bfr[f] = *reinterpret_cast<const s16x8*>(
            &Bsc[(wc + f * 16 + l15) * 64 + (((lg + kkc) ^ rx) << 3)]);
#pragma unroll
      for (int fi = 0; fi < FI; ++fi)
#pragma unroll
        for (int fj = 0; fj < FJ; ++fj)
          acc[fi][fj] = __builtin_amdgcn_mfma_f32_16x16x32_bf16(
              af[fi], bfr[fj], acc[fi][fj], 0, 0, 0);
    }
    __builtin_amdgcn_s_barrier();        // protect buf cur from next overwrite
    __builtin_amdgcn_sched_barrier(0);
    cur ^= 1;
  }

  if (MODE == 4) {
    // fused RoPE: cols<2048 are q|k (head-width 64, wave spans one head).
    const bool isqk = (tileN + wc) < 2048;
#pragma unroll
    for (int fi = 0; fi < FI; ++fi) {
#pragma unroll
      for (int fj = 0; fj < FJ; ++fj) {
#pragma unroll
        for (int r = 0; r < 4; ++r) {
          const int row = tileM + wr + fi * 16 + lg * 4 + r;
          const int col = tileN + wc + fj * 16 + l15;
          float a0 = acc[fi][fj][r] + p.bias[col];
          float vout;
          if (isqk) {
            float a1 = acc[fi][fj ^ 2][r] + p.bias[col ^ 32];
            const int dl = fj * 16 + l15;  // col & 63
            const float c = p.cosb[(size_t)row * HDm + dl];
            const float sn = p.sinb[(size_t)row * HDm + dl];
            vout = (fj < 2) ? (a0 * c - a1 * sn) : (a0 * c + a1 * sn);
          } else {
            vout = a0;
          }
          reinterpret_cast<short*>(Cb)[(size_t)row * p.ldc + col] = f2bf(vout);
        }
      }
    }
    return;
  }

#pragma unroll
  for (int fi = 0; fi < FI; ++fi) {
#pragma unroll
    for (int fj = 0; fj < FJ; ++fj) {
#pragma unroll
      for (int r = 0; r < 4; ++r) {
        const int row = tileM + wr + fi * 16 + lg * 4 + r;
        const int col = tileN + wc + fj * 16 + l15;
        float v = acc[fi][fj][r] * p.scale;
        if (BIAS) v += p.bias[col];
        if (GELU) v = 0.5f * v * (1.0f + erff(v * 0.70710678118654752f));
        if (RES) v += p.res[(size_t)row * p.ldres + col];
        if (OBF16)
          reinterpret_cast<short*>(Cb)[(size_t)row * p.ldc + col] = f2bf(v);
        else
          reinterpret_cast<float*>(Cb)[(size_t)row * p.ldc + col] = v;
      }
    }
  }
}

// ---- split-K reduce: out = sum(partials) + bias + res  (fp32) ----
template <int SPLIT>
__global__ __launch_bounds__(256) void fcred(const float* __restrict__ pb,
                                             const float* __restrict__ bias,
                                             const float* __restrict__ res,
                                             float* __restrict__ out) {
  const size_t i = ((size_t)blockIdx.x * 256 + threadIdx.x) * 4;
  f32x4 o = *reinterpret_cast<const f32x4*>(res + i);
  f32x4 bi = *reinterpret_cast<const f32x4*>(bias + (i & (Dm - 1)));
  o += bi;
#pragma unroll
  for (int s = 0; s < SPLIT; ++s)
    o += *reinterpret_cast<const f32x4*>(pb + (size_t)s * Sn * Dm + i);
  *reinterpret_cast<f32x4*>(out + i) = o;
}

extern "C" void kernel_launch(void* const* d_in, const int* in_sizes, int n_in,
                              void* d_out, int out_size, void* d_ws, size_t ws_size,
                              hipStream_t stream) {
  const float* x0 = (const float*)d_in[0];
  const float* cosb = (const float*)d_in[2];
  const float* sinb = (const float*)d_in[3];
  const float* ln1_g = (const float*)d_in[4];
  const float* ln1_b = (const float*)d_in[5];
  const float* qkv_w = (const float*)d_in[6];
  const float* qkv_b = (const float*)d_in[7];
  const float* proj_w = (const float*)d_in[8];
  const float* proj_b = (const float*)d_in[9];
  const float* ln2_g = (const float*)d_in[10];
  const float* ln2_b = (const float*)d_in[11];
  const float* fc1_w = (const float*)d_in[12];
  const float* fc1_b = (const float*)d_in[13];
  const float* fc2_w = (const float*)d_in[14];
  const float* fc2_b = (const float*)d_in[15];

  char* ws = (char*)d_ws;
  size_t off = 0;
  auto alloc = [&](size_t bytes) {
    void* p = ws + off;
    off += (bytes + 255) & ~(size_t)255;
    return p;
  };
  short* wqkvT = (short*)alloc((size_t)2 * 3072 * 1024 * 2);
  short* wprojT = (short*)alloc((size_t)2 * 1024 * 1024 * 2);
  short* wfc1T = (short*)alloc((size_t)2 * 4096 * 1024 * 2);
  short* wfc2T = (short*)alloc((size_t)2 * 1024 * 4096 * 2);
  float* xbuf = (float*)alloc((size_t)Sn * Dm * 4);
  short* hbuf = (short*)alloc((size_t)Sn * Dm * 2);
  short* qkvb = (short*)alloc((size_t)Sn * 3 * Dm * 2);   // q,k roped + v (bf16)
  short* probs = (short*)alloc((size_t)64 * SEG * SEG * 2);
  // scores fp32 (67MB); dead by FC2 time -> split-K partials (33.6MB) alias it.
  float* scores = (float*)alloc((size_t)64 * SEG * SEG * 4);
  float* pbuf = scores;
  short* ao = (short*)alloc((size_t)Sn * Dm * 2);
  short* ffn = (short*)alloc((size_t)Sn * FFm * 2);
  short* vT = ffn;  // vT (4.2MB) aliases ffn: dead during attention phase
  (void)ws_size; (void)in_sizes; (void)n_in; (void)out_size;

  // weight transpose+convert (per call; stateless)
  for (int i = 0; i < 2; ++i) {
    wt_kernel<<<dim3(96, 32), 256, 0, stream>>>(
        qkv_w + (size_t)i * Dm * 3072, wqkvT + (size_t)i * 3072 * Dm, Dm, 3072, 3072);
    wt_kernel<<<dim3(32, 32), 256, 0, stream>>>(
        proj_w + (size_t)i * Dm * Dm, wprojT + (size_t)i * Dm * Dm, Dm, Dm, Dm);
    wt_kernel<<<dim3(128, 32), 256, 0, stream>>>(
        fc1_w + (size_t)i * Dm * FFm, wfc1T + (size_t)i * FFm * Dm, Dm, FFm, FFm);
    wt_kernel<<<dim3(32, 128), 256, 0, stream>>>(
        fc2_w + (size_t)i * FFm * Dm, wfc2T + (size_t)i * Dm * FFm, FFm, Dm, Dm);
  }

  for (int i = 0; i < 2; ++i) {
    const float* xin = i ? (const float*)xbuf : x0;

    ln_kernel<<<dim3(Sn), 256, 0, stream>>>(xin, ln1_g + i * Dm, ln1_b + i * Dm, hbuf);

    {  // qkvb = rope(h @ Wqkv + b)  (bf16 out, rope on q,k cols)
      GemmArgs p = {};
      p.A = hbuf; p.lda = Dm;
      p.B = wqkvT + (size_t)i * 3072 * Dm; p.ldb = Dm;
      p.C = qkvb; p.ldc = 3 * Dm;
      p.M = Sn; p.N = 3 * Dm; p.K = Dm;
      p.bias = qkv_b + i * 3 * Dm; p.cosb = cosb; p.sinb = sinb; p.scale = 1.0f;
      gemm5<128, 128, 1, 4, 1, 1, 0, 0><<<dim3(24, 16, 1), 256, 0, stream>>>(p);
    }

    // v (bf16 cols 2048.. of qkvb) -> vT (coalesced LDS-tiled transpose)
    wtb_kernel<<<dim3(32, 64), 256, 0, stream>>>(qkvb + 2 * Dm, vT, Sn, Dm, 3 * Dm);

    {  // scores = scale * q @ k^T  per (head, seg)  (fp32 out)
      GemmArgs p = {};
      p.A = qkvb; p.lda = 3 * Dm;
      p.B = qkvb + Dm; p.ldb = 3 * Dm;
      p.C = scores; p.ldc = SEG;
      p.M = SEG; p.N = SEG; p.K = HDm;
      p.scale = 0.125f;
      gemm5<128, 128, 1, 1, 0, 0, 0, 0><<<dim3(4, 4, 64), 256, 0, stream>>>(p);
    }

    softmax_kernel<<<dim3(SEG, 64), 128, 0, stream>>>(scores, probs);

    {  // ao = probs @ V  per (head, seg)  (bf16 out)
      GemmArgs p = {};
      p.A = probs; p.lda = SEG;
      p.B = vT; p.ldb = Sn;
      p.C = ao; p.ldc = Dm;
      p.M = SEG; p.N = HDm; p.K = SEG;
      p.scale = 1.0f;
      gemm5<64, 64, 1, 2, 1, 0, 0, 0><<<dim3(1, 8, 64), 256, 0, stream>>>(p);
    }

    {  // x = xin + ao @ Wproj + b  (fp32 out)
      GemmArgs p = {};
      p.A = ao; p.lda = Dm;
      p.B = wprojT + (size_t)i * Dm * Dm; p.ldb = Dm;
      p.C = xbuf; p.ldc = Dm;
      p.M = Sn; p.N = Dm; p.K = Dm;
      p.bias = proj_b + i * Dm; p.res = xin; p.ldres = Dm; p.scale = 1.0f;
      gemm5<64, 64, 1, 0, 0, 1, 1, 0><<<dim3(16, 32, 1), 256, 0, stream>>>(p);
    }

    ln_kernel<<<dim3(Sn), 256, 0, stream>>>(xbuf, ln2_g + i * Dm, ln2_b + i * Dm, hbuf);

    {  // ffn = gelu(h2 @ Wfc1 + b)  (bf16 out)
      GemmArgs p = {};
      p.A = hbuf; p.lda = Dm;
      p.B = wfc1T + (size_t)i * FFm * Dm; p.ldb = Dm;
      p.C = ffn; p.ldc = FFm;
      p.M = Sn; p.N = FFm; p.K = Dm;
      p.bias = fc1_b + i * FFm; p.scale = 1.0f;
      gemm5<128, 128, 1, 0, 1, 1, 0, 1><<<dim3(32, 16, 1), 256, 0, stream>>>(p);
    }

    {  // pbuf[z] = ffn @ Wfc2 (split-K=4 partials, fp32)
      GemmArgs p = {};
      p.A = ffn; p.lda = FFm;
      p.B = wfc2T + (size_t)i * Dm * FFm; p.ldb = FFm;
      p.C = pbuf; p.ldc = Dm;
      p.M = Sn; p.N = Dm; p.K = FFm;
      p.scale = 1.0f;
      gemm5<128, 128, 4, 3, 0, 0, 0, 0><<<dim3(8, 16, 4), 256, 0, stream>>>(p);
    }
    {  // x = sum(partials) + bias + xbuf  (layer 2 -> d_out)
      float* outp = (i == 1) ? (float*)d_out : xbuf;
      fcred<4><<<dim3(Sn * Dm / 1024), 256, 0, stream>>>(pbuf, fc2_b + i * Dm, xbuf, outp);
    }
  }
}